// Round 1
// baseline (6884.882 us; speedup 1.0000x reference)
//
#include <hip/hip_runtime.h>
#include <math.h>

#define NN 511      // FFT size (2*256-1)
#define HH 256      // image H=W
#define BB 4
#define CINC 4
#define COUTC 8
#define CROP 127    // (H-1)//2 crop offset

// ---------------------------------------------------------------------------
// Twiddle matrix: D[k*NN+n] = exp(-2*pi*i * (k*n mod NN) / NN).  Symmetric.
// ---------------------------------------------------------------------------
__global__ void twiddle_kernel(float2* __restrict__ D) {
    int idx = blockIdx.x * blockDim.x + threadIdx.x;
    if (idx >= NN * NN) return;
    int k = idx / NN, n = idx % NN;
    int m = (int)(((long long)k * (long long)n) % NN);
    float phi = (float)(-2.0 * M_PI * (double)m / (double)NN);
    float s, c;
    sincosf(phi, &s, &c);
    D[idx] = make_float2(c, s);
}

// ---------------------------------------------------------------------------
// Stage A: T1[bc][u][x] = sum_y im[bc][y][x] * D[u][y]   (real * complex)
// block = (bc, u), threads over x (256). D row is wave-uniform (scalar path),
// im access coalesced.
// ---------------------------------------------------------------------------
__global__ void fft_cols_kernel(const float* __restrict__ im,
                                const float2* __restrict__ D,
                                float2* __restrict__ T1) {
    int u  = blockIdx.x % NN;
    int bc = blockIdx.x / NN;
    int x  = threadIdx.x;
    const float*  imp  = im + (size_t)bc * HH * HH;
    const float2* Drow = D + (size_t)u * NN;
    float ar = 0.f, ai = 0.f;
    #pragma unroll 4
    for (int y = 0; y < HH; ++y) {
        float v  = imp[(size_t)y * HH + x];
        float2 d = Drow[y];
        ar += v * d.x;
        ai += v * d.y;
    }
    T1[((size_t)bc * NN + u) * HH + x] = make_float2(ar, ai);
}

// ---------------------------------------------------------------------------
// Stage B: F[bc][u][v] = sum_x T1[bc][u][x] * D[v][x]
// D symmetric -> read D[x][v]: coalesced across v-threads. T1 row uniform.
// block = (bc, u), 512 threads over v (guard v<511).
// ---------------------------------------------------------------------------
__global__ void fft_rows_kernel(const float2* __restrict__ T1,
                                const float2* __restrict__ D,
                                float2* __restrict__ F) {
    int u  = blockIdx.x % NN;
    int bc = blockIdx.x / NN;
    int v  = threadIdx.x;
    if (v >= NN) return;
    const float2* t1row = T1 + ((size_t)bc * NN + u) * HH;
    float ar = 0.f, ai = 0.f;
    #pragma unroll 4
    for (int x = 0; x < HH; ++x) {
        float2 t = t1row[x];                    // uniform broadcast
        float2 d = D[(size_t)x * NN + v];       // coalesced
        ar += t.x * d.x - t.y * d.y;
        ai += t.x * d.y + t.y * d.x;
    }
    F[((size_t)bc * NN + u) * NN + v] = make_float2(ar, ai);
}

// ---------------------------------------------------------------------------
// Stage C: feats[b][o][uv] = sum_c F[b][c][uv] * W[o][c][uv]   (complex*complex)
// ---------------------------------------------------------------------------
__global__ void cmul_kernel(const float2* __restrict__ F,
                            const float2* __restrict__ W,
                            float2* __restrict__ feats) {
    size_t idx = (size_t)blockIdx.x * blockDim.x + threadIdx.x;
    const size_t total = (size_t)BB * COUTC * NN * NN;
    if (idx >= total) return;
    size_t uv = idx % ((size_t)NN * NN);
    int bo = (int)(idx / ((size_t)NN * NN));
    int o = bo % COUTC;
    int b = bo / COUTC;
    float ar = 0.f, ai = 0.f;
    #pragma unroll
    for (int c = 0; c < CINC; ++c) {
        float2 f = F[((size_t)(b * CINC + c)) * NN * NN + uv];
        float2 w = W[((size_t)(o * CINC + c)) * NN * NN + uv];
        ar += f.x * w.x - f.y * w.y;
        ai += f.x * w.y + f.y * w.x;
    }
    feats[idx] = make_float2(ar, ai);
}

// ---------------------------------------------------------------------------
// Stage D: T2[bo][u][x] = sum_v feats[bo][u][v] * conj(D[x+127][v])
// (D symmetric: conj(D[v][x+127]) = conj(D[x+127][v]))
// block = (bo, u), threads over x (256). feats row uniform; D rows 127..382
// are shared by ALL blocks -> L2-resident.
// ---------------------------------------------------------------------------
__global__ void ifft_rows_kernel(const float2* __restrict__ feats,
                                 const float2* __restrict__ D,
                                 float2* __restrict__ T2) {
    int u  = blockIdx.x % NN;
    int bo = blockIdx.x / NN;
    int x  = threadIdx.x;
    const float2* frow = feats + ((size_t)bo * NN + u) * NN;
    const float2* Drow = D + (size_t)(x + CROP) * NN;
    float ar = 0.f, ai = 0.f;
    #pragma unroll 4
    for (int v = 0; v < NN; ++v) {
        float2 f = frow[v];   // uniform broadcast
        float2 d = Drow[v];   // per-thread row, sequential within row
        // f * conj(d) = (fr*dx + fi*dy) + i(fi*dx - fr*dy)
        ar += f.x * d.x + f.y * d.y;
        ai += f.y * d.x - f.x * d.y;
    }
    T2[((size_t)bo * NN + u) * HH + x] = make_float2(ar, ai);
}

// ---------------------------------------------------------------------------
// Stage E: out[bo][y][x] = bias[o] + (1/NN^2) * Re( sum_u T2[bo][u][x] *
//                                                   conj(D[y+127][u]) )
// Re(t * conj(d)) = tr*dx + ti*dy.  T2 column access coalesced across x.
// block = (bo, y), threads over x (256).
// ---------------------------------------------------------------------------
__global__ void ifft_cols_kernel(const float2* __restrict__ T2,
                                 const float2* __restrict__ D,
                                 const float* __restrict__ bias,
                                 float* __restrict__ out) {
    int y  = blockIdx.x % HH;
    int bo = blockIdx.x / HH;
    int o  = bo % COUTC;
    int x  = threadIdx.x;
    const float2* t2   = T2 + (size_t)bo * NN * HH;
    const float2* Drow = D + (size_t)(y + CROP) * NN;
    float acc = 0.f;
    #pragma unroll 4
    for (int u = 0; u < NN; ++u) {
        float2 t = t2[(size_t)u * HH + x];  // coalesced
        float2 d = Drow[u];                 // uniform broadcast
        acc += t.x * d.x + t.y * d.y;
    }
    const float scale = 1.0f / ((float)NN * (float)NN);
    out[((size_t)bo * HH + y) * HH + x] = acc * scale + bias[o];
}

// ---------------------------------------------------------------------------
// kernel_launch
// ws layout: [D twiddle 2.09MB] [buf1 33.5MB: F then T2] [buf2 66.9MB: T1 then feats]
// ---------------------------------------------------------------------------
extern "C" void kernel_launch(void* const* d_in, const int* in_sizes, int n_in,
                              void* d_out, int out_size, void* d_ws, size_t ws_size,
                              hipStream_t stream) {
    const float*  im   = (const float*)d_in[0];
    const float2* W    = (const float2*)d_in[1];
    const float*  bias = (const float*)d_in[2];
    float*        out  = (float*)d_out;

    char* ws = (char*)d_ws;
    const size_t dBytes    = ((size_t)NN * NN * sizeof(float2) + 255) & ~(size_t)255;   // 2,089,216
    const size_t buf1Bytes = (size_t)BB * COUTC * NN * HH * sizeof(float2);             // 33,488,896 (multiple of 256)

    float2* D    = (float2*)ws;
    float2* buf1 = (float2*)(ws + dBytes);              // holds F (33.4MB), then T2 (33.5MB)
    float2* buf2 = (float2*)(ws + dBytes + buf1Bytes);  // holds T1 (16.7MB), then feats (66.8MB)

    // 1. twiddle matrix
    twiddle_kernel<<<(NN * NN + 255) / 256, 256, 0, stream>>>(D);

    // 2. FFT along columns: T1 in buf2
    fft_cols_kernel<<<BB * CINC * NN, 256, 0, stream>>>(im, D, buf2);

    // 3. FFT along rows: F in buf1
    fft_rows_kernel<<<BB * CINC * NN, 512, 0, stream>>>(buf2, D, buf1);

    // 4. pointwise complex MAC over cin: feats in buf2 (overwrites dead T1)
    {
        const size_t total = (size_t)BB * COUTC * NN * NN;
        cmul_kernel<<<(unsigned)((total + 255) / 256), 256, 0, stream>>>(buf1, W, buf2);
    }

    // 5. iFFT along rows: T2 in buf1 (overwrites dead F)
    ifft_rows_kernel<<<BB * COUTC * NN, 256, 0, stream>>>(buf2, D, buf1);

    // 6. iFFT along columns + crop + bias -> out
    ifft_cols_kernel<<<BB * COUTC * HH, 256, 0, stream>>>(buf1, D, bias, out);
}

// Round 2
// 961.930 us; speedup vs baseline: 7.1574x; 7.1574x over previous
//
#include <hip/hip_runtime.h>
#include <math.h>

#define NN 511      // FFT size (2*256-1)
#define HH 256      // image H=W
#define BB 4
#define CINC 4
#define COUTC 8
#define CROP 127    // (H-1)//2 crop offset
#define UT 4        // output rows per block (tiling factor)
#define UTILES ((NN + UT - 1) / UT)   // 128

// ---------------------------------------------------------------------------
// Twiddle matrix: D[k*NN+n] = exp(-2*pi*i * (k*n mod NN) / NN).  Symmetric.
// ---------------------------------------------------------------------------
__global__ void twiddle_kernel(float2* __restrict__ D) {
    int idx = blockIdx.x * blockDim.x + threadIdx.x;
    if (idx >= NN * NN) return;
    int k = idx / NN, n = idx % NN;
    int m = (int)(((long long)k * (long long)n) % NN);
    float phi = (float)(-2.0 * M_PI * (double)m / (double)NN);
    float s, c;
    sincosf(phi, &s, &c);
    D[idx] = make_float2(c, s);
}

// ---------------------------------------------------------------------------
// Stage A: T1[bc][u][x] = sum_y im[bc][y][x] * D[u][y]   (real * complex)
// Tiled: 4 u-rows per block. im loads coalesced (reused 4x); D broadcast.
// ---------------------------------------------------------------------------
__global__ void fft_cols_kernel(const float* __restrict__ im,
                                const float2* __restrict__ D,
                                float2* __restrict__ T1) {
    int ut = blockIdx.x % UTILES;
    int bc = blockIdx.x / UTILES;
    int u0 = ut * UT;
    int x  = threadIdx.x;
    const float* imp = im + (size_t)bc * HH * HH;
    const float2* Dr[UT];
    #pragma unroll
    for (int j = 0; j < UT; ++j) {
        int u = u0 + j; if (u >= NN) u = NN - 1;
        Dr[j] = D + (size_t)u * NN;
    }
    float ar[UT] = {0}, ai[UT] = {0};
    #pragma unroll 2
    for (int y = 0; y < HH; ++y) {
        float v = imp[(size_t)y * HH + x];   // coalesced, reused UT times
        #pragma unroll
        for (int j = 0; j < UT; ++j) {
            float2 d = Dr[j][y];             // uniform broadcast
            ar[j] += v * d.x;
            ai[j] += v * d.y;
        }
    }
    #pragma unroll
    for (int j = 0; j < UT; ++j) {
        int u = u0 + j;
        if (u < NN)
            T1[((size_t)bc * NN + u) * HH + x] = make_float2(ar[j], ai[j]);
    }
}

// ---------------------------------------------------------------------------
// Stage B: F[bc][u][v] = sum_x T1[bc][u][x] * D[v][x]
// D symmetric -> read D[x][v]: coalesced across v-threads (reused 4x).
// T1 rows uniform broadcast.  512 threads over v (guard v<511).
// ---------------------------------------------------------------------------
__global__ void fft_rows_kernel(const float2* __restrict__ T1,
                                const float2* __restrict__ D,
                                float2* __restrict__ F) {
    int ut = blockIdx.x % UTILES;
    int bc = blockIdx.x / UTILES;
    int u0 = ut * UT;
    int v  = threadIdx.x;
    int vc = v < NN ? v : NN - 1;
    const float2* t1r[UT];
    #pragma unroll
    for (int j = 0; j < UT; ++j) {
        int u = u0 + j; if (u >= NN) u = NN - 1;
        t1r[j] = T1 + ((size_t)bc * NN + u) * HH;
    }
    float ar[UT] = {0}, ai[UT] = {0};
    #pragma unroll 2
    for (int x = 0; x < HH; ++x) {
        float2 d = D[(size_t)x * NN + vc];   // coalesced, reused UT times
        #pragma unroll
        for (int j = 0; j < UT; ++j) {
            float2 t = t1r[j][x];            // uniform broadcast
            ar[j] += t.x * d.x - t.y * d.y;
            ai[j] += t.x * d.y + t.y * d.x;
        }
    }
    if (v < NN) {
        #pragma unroll
        for (int j = 0; j < UT; ++j) {
            int u = u0 + j;
            if (u < NN)
                F[((size_t)bc * NN + u) * NN + v] = make_float2(ar[j], ai[j]);
        }
    }
}

// ---------------------------------------------------------------------------
// Stage C: feats[b][o][uv] = sum_c F[b][c][uv] * W[o][c][uv]
// One thread per (b,uv); all COUT accumulated in registers so F is read once.
// ---------------------------------------------------------------------------
__global__ void cmul_kernel(const float2* __restrict__ F,
                            const float2* __restrict__ W,
                            float2* __restrict__ feats) {
    size_t t = (size_t)blockIdx.x * blockDim.x + threadIdx.x;
    const size_t NPIX = (size_t)NN * NN;
    if (t >= (size_t)BB * NPIX) return;
    int    b  = (int)(t / NPIX);
    size_t uv = t % NPIX;
    float2 f[CINC];
    #pragma unroll
    for (int c = 0; c < CINC; ++c)
        f[c] = F[((size_t)(b * CINC + c)) * NPIX + uv];
    #pragma unroll
    for (int o = 0; o < COUTC; ++o) {
        float ar = 0.f, ai = 0.f;
        #pragma unroll
        for (int c = 0; c < CINC; ++c) {
            float2 w = W[((size_t)(o * CINC + c)) * NPIX + uv];   // coalesced
            ar += f[c].x * w.x - f[c].y * w.y;
            ai += f[c].x * w.y + f[c].y * w.x;
        }
        feats[((size_t)(b * COUTC + o)) * NPIX + uv] = make_float2(ar, ai);
    }
}

// ---------------------------------------------------------------------------
// Stage D: T2[bo][u][x] = sum_v feats[bo][u][v] * conj(D[x+127][v])
// Symmetry: D[x+127][v] = D[v][x+127] -> load D[v*NN + x+127]: COALESCED
// across x-threads (the round-1 version read 64 cache lines/wave here).
// Tiled 4 u-rows per block; feats rows uniform broadcast.
// ---------------------------------------------------------------------------
__global__ void ifft_rows_kernel(const float2* __restrict__ feats,
                                 const float2* __restrict__ D,
                                 float2* __restrict__ T2) {
    int ut = blockIdx.x % UTILES;
    int bo = blockIdx.x / UTILES;
    int u0 = ut * UT;
    int x  = threadIdx.x;
    const float2* fr[UT];
    #pragma unroll
    for (int j = 0; j < UT; ++j) {
        int u = u0 + j; if (u >= NN) u = NN - 1;
        fr[j] = feats + ((size_t)bo * NN + u) * NN;
    }
    float ar[UT] = {0}, ai[UT] = {0};
    #pragma unroll 2
    for (int v = 0; v < NN; ++v) {
        float2 d = D[(size_t)v * NN + (x + CROP)];   // coalesced, reused UT times
        #pragma unroll
        for (int j = 0; j < UT; ++j) {
            float2 f = fr[j][v];                     // uniform broadcast
            // f * conj(d)
            ar[j] += f.x * d.x + f.y * d.y;
            ai[j] += f.y * d.x - f.x * d.y;
        }
    }
    #pragma unroll
    for (int j = 0; j < UT; ++j) {
        int u = u0 + j;
        if (u < NN)
            T2[((size_t)bo * NN + u) * HH + x] = make_float2(ar[j], ai[j]);
    }
}

// ---------------------------------------------------------------------------
// Stage E: out[bo][y][x] = bias[o] + (1/NN^2)*Re( sum_u T2[bo][u][x] *
//                                                 conj(D[y+127][u]) )
// Tiled 4 y-rows per block: T2 column loads (coalesced) reused 4x; D broadcast.
// ---------------------------------------------------------------------------
__global__ void ifft_cols_kernel(const float2* __restrict__ T2,
                                 const float2* __restrict__ D,
                                 const float* __restrict__ bias,
                                 float* __restrict__ out) {
    int yt = blockIdx.x % (HH / UT);
    int bo = blockIdx.x / (HH / UT);
    int o  = bo % COUTC;
    int y0 = yt * UT;
    int x  = threadIdx.x;
    const float2* t2 = T2 + (size_t)bo * NN * HH;
    const float2* Dr[UT];
    #pragma unroll
    for (int j = 0; j < UT; ++j)
        Dr[j] = D + (size_t)(y0 + j + CROP) * NN;
    float acc[UT] = {0};
    #pragma unroll 2
    for (int u = 0; u < NN; ++u) {
        float2 t = t2[(size_t)u * HH + x];   // coalesced, reused UT times
        #pragma unroll
        for (int j = 0; j < UT; ++j) {
            float2 d = Dr[j][u];             // uniform broadcast
            acc[j] += t.x * d.x + t.y * d.y;
        }
    }
    const float scale = 1.0f / ((float)NN * (float)NN);
    float bv = bias[o];
    #pragma unroll
    for (int j = 0; j < UT; ++j)
        out[((size_t)bo * HH + (y0 + j)) * HH + x] = acc[j] * scale + bv;
}

// ---------------------------------------------------------------------------
// kernel_launch
// ws layout: [D twiddle 2.09MB] [buf1 33.5MB: F then T2] [buf2 66.9MB: T1 then feats]
// ---------------------------------------------------------------------------
extern "C" void kernel_launch(void* const* d_in, const int* in_sizes, int n_in,
                              void* d_out, int out_size, void* d_ws, size_t ws_size,
                              hipStream_t stream) {
    const float*  im   = (const float*)d_in[0];
    const float2* W    = (const float2*)d_in[1];
    const float*  bias = (const float*)d_in[2];
    float*        out  = (float*)d_out;

    char* ws = (char*)d_ws;
    const size_t dBytes    = ((size_t)NN * NN * sizeof(float2) + 255) & ~(size_t)255;
    const size_t buf1Bytes = (size_t)BB * COUTC * NN * HH * sizeof(float2);

    float2* D    = (float2*)ws;
    float2* buf1 = (float2*)(ws + dBytes);              // F, then T2
    float2* buf2 = (float2*)(ws + dBytes + buf1Bytes);  // T1, then feats

    // 1. twiddle matrix
    twiddle_kernel<<<(NN * NN + 255) / 256, 256, 0, stream>>>(D);

    // 2. FFT along columns: T1 in buf2
    fft_cols_kernel<<<BB * CINC * UTILES, 256, 0, stream>>>(im, D, buf2);

    // 3. FFT along rows: F in buf1
    fft_rows_kernel<<<BB * CINC * UTILES, 512, 0, stream>>>(buf2, D, buf1);

    // 4. pointwise complex MAC over cin: feats in buf2 (overwrites dead T1)
    {
        const size_t total = (size_t)BB * NN * NN;
        cmul_kernel<<<(unsigned)((total + 255) / 256), 256, 0, stream>>>(buf1, W, buf2);
    }

    // 5. iFFT along rows: T2 in buf1 (overwrites dead F)
    ifft_rows_kernel<<<BB * COUTC * UTILES, 256, 0, stream>>>(buf2, D, buf1);

    // 6. iFFT along columns + crop + bias -> out
    ifft_cols_kernel<<<BB * COUTC * (HH / UT), 256, 0, stream>>>(buf1, D, bias, out);
}

// Round 3
// 257.908 us; speedup vs baseline: 26.6952x; 3.7297x over previous
//
#include <hip/hip_runtime.h>
#include <math.h>

#define NN 511
#define HH 256
#define BB 4
#define CINC 4
#define COUTC 8
#define CROP 127

typedef _Float16 f16;
typedef _Float16 f16x8 __attribute__((ext_vector_type(8)));
typedef float    f32x4 __attribute__((ext_vector_type(4)));

// dr(a,b) = cos(2*pi*((a*b)%511)/511), di(a,b) = -sin(...)   [forward twiddle]
__device__ __forceinline__ void twid(int a, int b, float& c, float& s) {
    int m = (int)(((long long)a * (long long)b) % NN);
    float phi = (float)(2.0 * M_PI / (double)NN) * (float)m;
    __sincosf(phi, &s, &c);   // s = sin(phi), c = cos(phi);  di = -s
}

// ---------------------------------------------------------------------------
// Prep kernels: build f16 twiddle matrices (K padded to mult of 32, zeros).
// ---------------------------------------------------------------------------
// Aa [1024 x 256]: rows<511 = dr(u,y); 511..1021 = di(u-511,y); else 0
__global__ void prep_Aa(f16* __restrict__ Aa) {
    int idx = blockIdx.x * 256 + threadIdx.x;   // 1024*256
    int m = idx >> 8, y = idx & 255;
    float c, s, v = 0.f;
    if (m < NN)            { twid(m, y, c, s);       v = c;  }
    else if (m < 2 * NN)   { twid(m - NN, y, c, s);  v = -s; }
    Aa[idx] = (f16)v;
}
// Bb_t [1024 x 512]: n<511 (v=n): k<256 ? dr(v,x) : -di(v,x)=+s
//                    511<=n<1022 (v=n-511): k<256 ? di=-s : dr=c ; n>=1022: 0
__global__ void prep_Bb(f16* __restrict__ Bb) {
    int idx = blockIdx.x * 256 + threadIdx.x;   // 1024*512
    int n = idx >> 9, k = idx & 511;
    float v = 0.f;
    if (n < 2 * NN) {
        int vv = (n < NN) ? n : n - NN;
        int x  = k & 255;
        float c, s; twid(vv, x, c, s);
        if (n < NN) v = (k < 256) ? c : s;
        else        v = (k < 256) ? -s : c;
    }
    Bb[idx] = (f16)v;
}
// Bd_t [512 x 1024]: n<256 (x=n): k<511 ? dr(v,x+127)=c : di=-s
//                    n>=256: k<511 ? -di=+s : dr=c ;  k>=1022: 0
__global__ void prep_Bd(f16* __restrict__ Bd) {
    int idx = blockIdx.x * 256 + threadIdx.x;   // 512*1024
    int n = idx >> 10, k = idx & 1023;
    float v = 0.f;
    if (k < 2 * NN) {
        int x  = n & 255;
        int vv = (k < NN) ? k : k - NN;
        float c, s; twid(vv, x + CROP, c, s);
        if (n < 256) v = (k < NN) ? c : -s;
        else         v = (k < NN) ? s : c;
    }
    Bd[idx] = (f16)v;
}
// Ae [256 x 1024]: k<511 ? dr(y+127,u)=c : di=-s ; k>=1022: 0
__global__ void prep_Ae(f16* __restrict__ Ae) {
    int idx = blockIdx.x * 256 + threadIdx.x;   // 256*1024
    int y = idx >> 10, k = idx & 1023;
    float v = 0.f;
    if (k < 2 * NN) {
        int u = (k < NN) ? k : k - NN;
        float c, s; twid(y + CROP, u, c, s);
        v = (k < NN) ? c : -s;
    }
    Ae[idx] = (f16)v;
}
// imT [16][256x256]: imT[bc][x][y] = im[bc][y][x]  (f16)
__global__ void prep_imT(const float* __restrict__ im, f16* __restrict__ imT) {
    int idx = blockIdx.x * 256 + threadIdx.x;   // 16*65536
    int bc = idx >> 16, r = idx & 65535;
    int y = r >> 8, x = r & 255;
    imT[(size_t)bc * 65536 + x * 256 + y] = (f16)im[idx];
}
// zero T2t pad cols 1022,1023 for all 32*256 rows (stage-D never writes them)
__global__ void zero_t2pad(f16* __restrict__ T2t) {
    int row = blockIdx.x * 256 + threadIdx.x;   // 8192
    T2t[(size_t)row * 1024 + 1022] = (f16)0.f;
    T2t[(size_t)row * 1024 + 1023] = (f16)0.f;
}

// ---------------------------------------------------------------------------
// Stage C: feats[(b*8+o)*511+u][v | 511+v] = sum_c F(b,c)*W(o,c)   (f16 io)
// ---------------------------------------------------------------------------
__global__ void cmul16(const f16* __restrict__ F, const float2* __restrict__ W,
                       f16* __restrict__ feats) {
    size_t t = (size_t)blockIdx.x * 256 + threadIdx.x;
    if (t >= (size_t)BB * NN * NN) return;
    int b = (int)(t / (NN * NN));
    int rem = (int)(t % (NN * NN));
    int u = rem / NN, v = rem % NN;
    float fr[CINC], fi[CINC];
    #pragma unroll
    for (int c = 0; c < CINC; ++c) {
        size_t row = ((size_t)(b * CINC + c) * NN + u) * 1024;
        fr[c] = (float)F[row + v];
        fi[c] = (float)F[row + NN + v];
    }
    #pragma unroll
    for (int o = 0; o < COUTC; ++o) {
        float ar = 0.f, ai = 0.f;
        #pragma unroll
        for (int c = 0; c < CINC; ++c) {
            float2 w = W[((size_t)(o * CINC + c) * NN + u) * NN + v];
            ar += fr[c] * w.x - fi[c] * w.y;
            ai += fr[c] * w.y + fi[c] * w.x;
        }
        size_t orow = ((size_t)(b * COUTC + o) * NN + u) * 1024;
        feats[orow + v]      = (f16)ar;
        feats[orow + NN + v] = (f16)ai;
        if (v == 0) { feats[orow + 1022] = (f16)0.f; feats[orow + 1023] = (f16)0.f; }
    }
}

// ---------------------------------------------------------------------------
// Generic MFMA GEMM: C[M,N] = A[M,K] x B[K,N], B stored transposed Bt[N,K].
// f16 in, fp32 acc. Block 64x64, BK=32, 4 waves (2x2), wave tile 32x32.
// Buffers are M/N/K padded; epilogue guards real extents.
// ---------------------------------------------------------------------------
#define INV_NN2 (1.0f / ((float)NN * (float)NN))

template<int EPI>
__global__ __launch_bounds__(256)
void gemm16(const f16* __restrict__ A, const f16* __restrict__ Bt,
            f16* __restrict__ Ch, float* __restrict__ Cf,
            const float* __restrict__ bias,
            int Kt, int ldA, int ldB, size_t sA, size_t sB) {
    __shared__ __align__(16) f16 As[64 * 40];
    __shared__ __align__(16) f16 Bs[64 * 40];

    const int z  = blockIdx.z;
    const int m0 = blockIdx.x * 64;
    const int n0 = blockIdx.y * 64;
    A  += (size_t)z * sA;
    Bt += (size_t)z * sB;

    const int t    = threadIdx.x;
    const int arow = t >> 2;
    const int ak   = (t & 3) << 3;
    const f16* Ap = A  + (size_t)(m0 + arow) * ldA + ak;
    const f16* Bp = Bt + (size_t)(n0 + arow) * ldB + ak;
    f16* wA = &As[arow * 40 + ak];
    f16* wB = &Bs[arow * 40 + ak];

    const int lane = t & 63, w = t >> 6;
    const int wm = (w >> 1) * 32, wn = (w & 1) * 32;
    const int col = lane & 15, quad = lane >> 4;
    const f16* a0 = &As[(wm + col) * 40 + quad * 8];
    const f16* b0 = &Bs[(wn + col) * 40 + quad * 8];

    f32x4 acc[2][2] = {};

    for (int kb = 0; kb < Kt; ++kb) {
        float4 va = *(const float4*)Ap;
        float4 vb = *(const float4*)Bp;
        __syncthreads();
        *(float4*)wA = va;
        *(float4*)wB = vb;
        __syncthreads();
        f16x8 af0 = *(const f16x8*)(a0);
        f16x8 af1 = *(const f16x8*)(a0 + 16 * 40);
        f16x8 bf0 = *(const f16x8*)(b0);
        f16x8 bf1 = *(const f16x8*)(b0 + 16 * 40);
        acc[0][0] = __builtin_amdgcn_mfma_f32_16x16x32_f16(af0, bf0, acc[0][0], 0, 0, 0);
        acc[0][1] = __builtin_amdgcn_mfma_f32_16x16x32_f16(af0, bf1, acc[0][1], 0, 0, 0);
        acc[1][0] = __builtin_amdgcn_mfma_f32_16x16x32_f16(af1, bf0, acc[1][0], 0, 0, 0);
        acc[1][1] = __builtin_amdgcn_mfma_f32_16x16x32_f16(af1, bf1, acc[1][1], 0, 0, 0);
        Ap += 32; Bp += 32;
    }

    #pragma unroll
    for (int i = 0; i < 2; ++i)
    #pragma unroll
    for (int j = 0; j < 2; ++j) {
        const int mbase = m0 + wm + i * 16 + quad * 4;
        const int ncol  = n0 + wn + j * 16 + col;
        #pragma unroll
        for (int r = 0; r < 4; ++r) {
            const int mm = mbase + r;
            const float val = acc[i][j][r];
            if constexpr (EPI == 0) {          // stage A -> T1 [8192 x 512]
                if (mm < 2 * NN) {
                    int u = (mm < NN) ? mm : mm - NN;
                    int c = (mm < NN) ? ncol : 256 + ncol;
                    Ch[((size_t)(z * NN + u)) * 512 + c] = (f16)val;
                }
            } else if constexpr (EPI == 1) {   // stage B -> F [8192 x 1024]
                if (mm < 16 * NN && ncol < 2 * NN)
                    Ch[(size_t)mm * 1024 + ncol] = (f16)val;
            } else if constexpr (EPI == 2) {   // stage D -> T2t [32][256 x 1024]
                if (mm < 32 * NN) {
                    int bo = mm / NN;
                    int u  = mm - bo * NN;
                    int x  = ncol & 255;
                    int k  = (ncol < 256) ? u : NN + u;
                    Ch[(size_t)bo * 262144 + (size_t)x * 1024 + k] = (f16)(val * INV_NN2);
                }
            } else {                            // stage E -> out fp32 [bo][256x256]
                Cf[(size_t)z * 65536 + (size_t)mm * 256 + ncol] = val + bias[z & 7];
            }
        }
    }
}

// ---------------------------------------------------------------------------
// kernel_launch
// ---------------------------------------------------------------------------
extern "C" void kernel_launch(void* const* d_in, const int* in_sizes, int n_in,
                              void* d_out, int out_size, void* d_ws, size_t ws_size,
                              hipStream_t stream) {
    const float*  im   = (const float*)d_in[0];
    const float2* W    = (const float2*)d_in[1];
    const float*  bias = (const float*)d_in[2];
    float*        out  = (float*)d_out;

    char* ws = (char*)d_ws;
    f16* Aa    = (f16*)(ws);                        // 1024*256
    f16* Bb    = (f16*)(ws + 524288);               // 1024*512
    f16* Bd    = (f16*)(ws + 1572864);              // 512*1024
    f16* Ae    = (f16*)(ws + 2621440);              // 256*1024
    f16* imT   = (f16*)(ws + 3145728);              // 16*256*256
    f16* T1    = (f16*)(ws + 5242880);              // 8192*512
    f16* F     = (f16*)(ws + 13631488);             // 8192*1024
    f16* feats = (f16*)(ws + 30408704);             // 16384*1024
    f16* T2t   = (f16*)(ws + 63963136);             // 32*256*1024

    // preps
    prep_Aa <<<1024, 256, 0, stream>>>(Aa);
    prep_Bb <<<2048, 256, 0, stream>>>(Bb);
    prep_Bd <<<2048, 256, 0, stream>>>(Bd);
    prep_Ae <<<1024, 256, 0, stream>>>(Ae);
    prep_imT<<<4096, 256, 0, stream>>>(im, imT);
    zero_t2pad<<<32, 256, 0, stream>>>(T2t);

    // Stage A: per bc: C[1022(->1024) x 256] = Aa[1024x256(K)] x imT  -> T1
    gemm16<0><<<dim3(16, 4, 16), 256, 0, stream>>>(Aa, imT, T1, nullptr, nullptr,
                                                   8, 256, 256, 0, 65536);
    // Stage B: C[8176(->8192) x 1022(->1024)] = T1[.,512] x Bb -> F
    gemm16<1><<<dim3(128, 16, 1), 256, 0, stream>>>(T1, Bb, F, nullptr, nullptr,
                                                    16, 512, 512, 0, 0);
    // Stage C: channel mix (pointwise complex), f16 io
    cmul16<<<4081, 256, 0, stream>>>(F, W, feats);
    // Stage D: C[16352(->16384) x 512] = feats[.,1024] x Bd -> T2t (scaled)
    gemm16<2><<<dim3(256, 8, 1), 256, 0, stream>>>(feats, Bd, T2t, nullptr, nullptr,
                                                   32, 1024, 1024, 0, 0);
    // Stage E: per bo: C[256 x 256] = Ae[256x1024] x T2t[bo] + bias -> out
    gemm16<3><<<dim3(4, 4, 32), 256, 0, stream>>>(Ae, T2t, nullptr, out, bias,
                                                  32, 1024, 1024, 0, 262144);
}

// Round 4
// 227.951 us; speedup vs baseline: 30.2033x; 1.1314x over previous
//
#include <hip/hip_runtime.h>
#include <math.h>

#define NN 511
#define HH 256
#define BB 4
#define CINC 4
#define COUTC 8
#define CROP 127
#define INV_NN2 (1.0f / ((float)NN * (float)NN))

typedef _Float16 f16;
typedef _Float16 f16x8 __attribute__((ext_vector_type(8)));
typedef float    f32x4 __attribute__((ext_vector_type(4)));

__device__ __forceinline__ void twid(int a, int b, float& c, float& s) {
    int m = (int)(((long long)a * (long long)b) % NN);
    float phi = (float)(2.0 * M_PI / (double)NN) * (float)m;
    __sincosf(phi, &s, &c);   // forward twiddle = c - i*s
}

// ---------------------------------------------------------------------------
// Prep kernels (twiddle-matrix factories, f16, padded with zeros)
// ---------------------------------------------------------------------------
// Aa [1024 x 256]: rows<511 = cos(u,y); 511..1021 = -sin(u-511,y); else 0
__global__ void prep_Aa(f16* __restrict__ Aa) {
    int idx = blockIdx.x * 256 + threadIdx.x;
    int m = idx >> 8, y = idx & 255;
    float c, s, v = 0.f;
    if (m < NN)          { twid(m, y, c, s);      v = c;  }
    else if (m < 2 * NN) { twid(m - NN, y, c, s); v = -s; }
    Aa[idx] = (f16)v;
}
// Bb_t [1024 x 512] (N,K layout)
__global__ void prep_Bb(f16* __restrict__ Bb) {
    int idx = blockIdx.x * 256 + threadIdx.x;
    int n = idx >> 9, k = idx & 511;
    float v = 0.f;
    if (n < 2 * NN) {
        int vv = (n < NN) ? n : n - NN;
        int x  = k & 255;
        float c, s; twid(vv, x, c, s);
        if (n < NN) v = (k < 256) ? c : s;
        else        v = (k < 256) ? -s : c;
    }
    Bb[idx] = (f16)v;
}
// Bd_t [512 x 1024] (N,K layout)
__global__ void prep_Bd(f16* __restrict__ Bd) {
    int idx = blockIdx.x * 256 + threadIdx.x;
    int n = idx >> 10, k = idx & 1023;
    float v = 0.f;
    if (k < 2 * NN) {
        int x  = n & 255;
        int vv = (k < NN) ? k : k - NN;
        float c, s; twid(vv, x + CROP, c, s);
        if (n < 256) v = (k < NN) ? c : -s;
        else         v = (k < NN) ? s : c;
    }
    Bd[idx] = (f16)v;
}
// Ae [256 x 1024]
__global__ void prep_Ae(f16* __restrict__ Ae) {
    int idx = blockIdx.x * 256 + threadIdx.x;
    int y = idx >> 10, k = idx & 1023;
    float v = 0.f;
    if (k < 2 * NN) {
        int u = (k < NN) ? k : k - NN;
        float c, s; twid(y + CROP, u, c, s);
        v = (k < NN) ? c : -s;
    }
    Ae[idx] = (f16)v;
}
// imT [16][256x256]: imT[bc][x][y] = im[bc][y][x]  (f16)
__global__ void prep_imT(const float* __restrict__ im, f16* __restrict__ imT) {
    int idx = blockIdx.x * 256 + threadIdx.x;
    int bc = idx >> 16, r = idx & 65535;
    int y = r >> 8, x = r & 255;
    imT[(size_t)bc * 65536 + x * 256 + y] = (f16)im[idx];
}
// zero pad cols 1022,1023 of a [rows x 1024] f16 buffer
__global__ void zero_pad1024(f16* __restrict__ buf, int rows) {
    int r = blockIdx.x * 256 + threadIdx.x;
    if (r < rows) {
        buf[(size_t)r * 1024 + 1022] = (f16)0.f;
        buf[(size_t)r * 1024 + 1023] = (f16)0.f;
    }
}

// ---------------------------------------------------------------------------
// Stage C: channel mix. One thread per (u,v); loops b,o,c. W fetched ONCE.
// ---------------------------------------------------------------------------
__global__ void cmul16(const f16* __restrict__ F, const float2* __restrict__ W,
                       f16* __restrict__ feats) {
    int idx = blockIdx.x * 256 + threadIdx.x;
    if (idx >= NN * NN) return;
    int u = idx / NN, v = idx % NN;
    float fr[BB][CINC], fi[BB][CINC];
    #pragma unroll
    for (int b = 0; b < BB; ++b)
        #pragma unroll
        for (int c = 0; c < CINC; ++c) {
            size_t row = ((size_t)(b * CINC + c) * NN + u) * 1024;
            fr[b][c] = (float)F[row + v];
            fi[b][c] = (float)F[row + NN + v];
        }
    #pragma unroll
    for (int o = 0; o < COUTC; ++o) {
        float2 w[CINC];
        #pragma unroll
        for (int c = 0; c < CINC; ++c)
            w[c] = W[((size_t)(o * CINC + c) * NN + u) * NN + v];
        #pragma unroll
        for (int b = 0; b < BB; ++b) {
            float ar = 0.f, ai = 0.f;
            #pragma unroll
            for (int c = 0; c < CINC; ++c) {
                ar += fr[b][c] * w[c].x - fi[b][c] * w[c].y;
                ai += fr[b][c] * w[c].y + fi[b][c] * w[c].x;
            }
            size_t orow = ((size_t)(b * COUTC + o) * NN + u) * 1024;
            feats[orow + v]      = (f16)ar;
            feats[orow + NN + v] = (f16)ai;
        }
    }
}

// ---------------------------------------------------------------------------
// m97-style MFMA GEMM: 128x128 block tile, 4 waves (2x2) x 64x64 wave tile,
// BK=32, global_load_lds(16B) staging, unpadded LDS (64B rows -> 2-way = free)
// A [M,K] row-major, Bt [N,K] row-major. f16 in, fp32 acc.
// ---------------------------------------------------------------------------
#define GLB_PTR(p) ((const __attribute__((address_space(1))) unsigned int*)(p))
#define LDS_PTR(p) ((__attribute__((address_space(3))) unsigned int*)(p))
__device__ __forceinline__ void gld16(const f16* g, f16* l) {
    __builtin_amdgcn_global_load_lds(GLB_PTR(g), LDS_PTR(l), 16, 0, 0);
}

template<int EPI>
__global__ __launch_bounds__(256)
void gemm128(const f16* __restrict__ A, const f16* __restrict__ Bt,
             f16* __restrict__ Ch, float* __restrict__ Cf,
             const float* __restrict__ bias,
             int Kt, int ldA, int ldB, size_t sA, size_t sB) {
    __shared__ __align__(16) f16 As[128 * 32];
    __shared__ __align__(16) f16 Bs[128 * 32];

    const int z  = blockIdx.z;
    const int m0 = blockIdx.x * 128;
    const int n0 = blockIdx.y * 128;
    A  += (size_t)z * sA;
    Bt += (size_t)z * sB;

    const int t  = threadIdx.x;
    const int r4 = t >> 2;            // 0..63: row within half-tile
    const int c8 = (t & 3) << 3;      // k-offset (f16): 0,8,16,24
    const f16* Ap = A  + (size_t)(m0 + r4) * ldA + c8;
    const f16* Bp = Bt + (size_t)(n0 + r4) * ldB + c8;
    f16* lA = As + t * 8;             // lane-contiguous 16B slots
    f16* lB = Bs + t * 8;

    const int lane = t & 63, w = t >> 6;
    const int wm = (w >> 1) * 64, wn = (w & 1) * 64;
    const int col = lane & 15, quad = lane >> 4;
    const f16* a_base = As + (wm + col) * 32 + quad * 8;
    const f16* b_base = Bs + (wn + col) * 32 + quad * 8;

    f32x4 acc[4][4] = {};

    for (int kb = 0; kb < Kt; ++kb) {
        __syncthreads();                    // all waves done reading prev tile
        gld16(Ap,            lA);
        gld16(Ap + 64 * ldA, lA + 2048);
        gld16(Bp,            lB);
        gld16(Bp + 64 * ldB, lB + 2048);
        Ap += 32; Bp += 32;
        __syncthreads();                    // vmcnt(0) drain -> staging done
        f16x8 af[4], bf[4];
        #pragma unroll
        for (int i = 0; i < 4; ++i) {
            af[i] = *(const f16x8*)(a_base + i * 16 * 32);
            bf[i] = *(const f16x8*)(b_base + i * 16 * 32);
        }
        #pragma unroll
        for (int i = 0; i < 4; ++i)
            #pragma unroll
            for (int j = 0; j < 4; ++j)
                acc[i][j] = __builtin_amdgcn_mfma_f32_16x16x32_f16(af[i], bf[j], acc[i][j], 0, 0, 0);
    }

    #pragma unroll
    for (int i = 0; i < 4; ++i)
    #pragma unroll
    for (int j = 0; j < 4; ++j) {
        const int mbase = m0 + wm + i * 16 + quad * 4;
        const int ncol  = n0 + wn + j * 16 + col;
        #pragma unroll
        for (int r = 0; r < 4; ++r) {
            const int mm = mbase + r;
            const float val = acc[i][j][r];
            if constexpr (EPI == 0) {          // stage A -> T1 [8192 x 512]
                if (mm < 2 * NN) {
                    int u = (mm < NN) ? mm : mm - NN;
                    int c = (mm < NN) ? ncol : 256 + ncol;
                    Ch[((size_t)(z * NN + u)) * 512 + c] = (f16)val;
                }
            } else if constexpr (EPI == 1) {   // stage B -> F [8192 x 1024]
                if (mm < 16 * NN && ncol < 2 * NN)
                    Ch[(size_t)mm * 1024 + ncol] = (f16)val;
            } else if constexpr (EPI == 2) {   // stage D -> T2t [32][256 x 1024]
                if (mm < 32 * NN) {
                    int bo = mm / NN;
                    int u  = mm - bo * NN;
                    int x  = ncol & 255;
                    int k  = (ncol < 256) ? u : NN + u;
                    Ch[(size_t)bo * 262144 + (size_t)x * 1024 + k] = (f16)(val * INV_NN2);
                }
            } else {                            // stage E -> out fp32
                int bo = ncol >> 8, x = ncol & 255;
                Cf[((size_t)bo * 256 + mm) * 256 + x] = val + bias[bo & 7];
            }
        }
    }
}

// ---------------------------------------------------------------------------
// kernel_launch
// ---------------------------------------------------------------------------
extern "C" void kernel_launch(void* const* d_in, const int* in_sizes, int n_in,
                              void* d_out, int out_size, void* d_ws, size_t ws_size,
                              hipStream_t stream) {
    const float*  im   = (const float*)d_in[0];
    const float2* W    = (const float2*)d_in[1];
    const float*  bias = (const float*)d_in[2];
    float*        out  = (float*)d_out;

    char* ws = (char*)d_ws;
    f16* Aa    = (f16*)(ws);                        // 1024*256   = 512 KB
    f16* Bb    = (f16*)(ws + 524288);               // 1024*512   = 1 MB
    f16* Bd    = (f16*)(ws + 1572864);              // 512*1024   = 1 MB
    f16* Ae    = (f16*)(ws + 2621440);              // 256*1024   = 512 KB
    f16* imT   = (f16*)(ws + 3145728);              // 16*256*256 = 2 MB
    f16* T1    = (f16*)(ws + 5242880);              // 8192*512   = 8 MB
    f16* F     = (f16*)(ws + 13631488);             // 8192*1024  = 16 MB
    f16* feats = (f16*)(ws + 30408704);             // 16384*1024 = 32 MB
    f16* T2t   = (f16*)(ws + 63963136);             // 8192*1024  = 16 MB

    // preps
    prep_Aa <<<1024, 256, 0, stream>>>(Aa);
    prep_Bb <<<2048, 256, 0, stream>>>(Bb);
    prep_Bd <<<2048, 256, 0, stream>>>(Bd);
    prep_Ae <<<1024, 256, 0, stream>>>(Ae);
    prep_imT<<<4096, 256, 0, stream>>>(im, imT);
    zero_pad1024<<<64, 256, 0, stream>>>(feats, 16384);
    zero_pad1024<<<32, 256, 0, stream>>>(T2t, 8192);

    // Stage A: per bc: [1024 x 256] = Aa[1024xK256] x imT[bc] -> T1
    gemm128<0><<<dim3(8, 2, 16), 256, 0, stream>>>(Aa, imT, T1, nullptr, nullptr,
                                                   8, 256, 256, 0, 65536);
    // Stage B: [8192 x 1024] = T1 x Bb -> F
    gemm128<1><<<dim3(64, 8, 1), 256, 0, stream>>>(T1, Bb, F, nullptr, nullptr,
                                                   16, 512, 512, 0, 0);
    // Stage C: channel mix
    cmul16<<<(NN * NN + 255) / 256, 256, 0, stream>>>(F, W, feats);
    // Stage D: [16384 x 512] = feats x Bd -> T2t (scaled by 1/NN^2)
    gemm128<2><<<dim3(128, 4, 1), 256, 0, stream>>>(feats, Bd, T2t, nullptr, nullptr,
                                                    32, 1024, 1024, 0, 0);
    // Stage E: [256 x 8192] = Ae x T2t + bias -> out
    gemm128<3><<<dim3(2, 64, 1), 256, 0, stream>>>(Ae, T2t, nullptr, out, bias,
                                                   32, 1024, 1024, 0, 0);
}

// Round 5
// 181.919 us; speedup vs baseline: 37.8459x; 1.2530x over previous
//
#include <hip/hip_runtime.h>
#include <math.h>

#define NN 511
#define HH 256
#define BB 4
#define CINC 4
#define COUTC 8
#define CROP 127
#define INV_NN2 (1.0f / ((float)NN * (float)NN))

typedef _Float16 f16;
typedef _Float16 f16x8 __attribute__((ext_vector_type(8)));
typedef float    f32x4 __attribute__((ext_vector_type(4)));

__device__ __forceinline__ void twid(int a, int b, float& c, float& s) {
    int m = (int)(((long long)a * (long long)b) % NN);
    float phi = (float)(2.0 * M_PI / (double)NN) * (float)m;
    __sincosf(phi, &s, &c);   // forward twiddle = c - i*s
}

// ---------------------------------------------------------------------------
// Prep kernels (f16 twiddle factories). Hermitian halving: only u in [0,256).
// ---------------------------------------------------------------------------
// Aa_h [512 x 256]: m<256: Re D[m,y]=c ; m>=256: Im D[m-256,y]=-s
__global__ void prep_Aa(f16* __restrict__ Aa) {
    int idx = blockIdx.x * 256 + threadIdx.x;   // 512*256
    int m = idx >> 8, y = idx & 255;
    float c, s;
    if (m < 256) { twid(m, y, c, s);      Aa[idx] = (f16)c;    }
    else         { twid(m - 256, y, c, s); Aa[idx] = (f16)(-s); }
}
// Bb_t [1024 x 512] (N,K): n<511 -> Fr row v=n ; 511..1021 -> Fi row v=n-511
__global__ void prep_Bb(f16* __restrict__ Bb) {
    int idx = blockIdx.x * 256 + threadIdx.x;   // 1024*512
    int n = idx >> 9, k = idx & 511;
    float v = 0.f;
    if (n < 2 * NN) {
        int vv = (n < NN) ? n : n - NN;
        int x  = k & 255;
        float c, s; twid(vv, x, c, s);
        if (n < NN) v = (k < 256) ? c : s;
        else        v = (k < 256) ? -s : c;
    }
    Bb[idx] = (f16)v;
}
// Bd_t [512 x 1024] (N,K): n<256: T2r at x=n ; n>=256: T2i at x=n-256
// T2r: k<511 ? c(v(x+127)) : -s ; T2i: k<511 ? s : c  (k>=1022: 0)
__global__ void prep_Bd(f16* __restrict__ Bd) {
    int idx = blockIdx.x * 256 + threadIdx.x;   // 512*1024
    int n = idx >> 10, k = idx & 1023;
    float v = 0.f;
    if (k < 2 * NN) {
        int x  = n & 255;
        int vv = (k < NN) ? k : k - NN;
        float c, s; twid(vv, x + CROP, c, s);
        if (n < 256) v = (k < NN) ? c : -s;
        else         v = (k < NN) ? s : c;
    }
    Bd[idx] = (f16)v;
}
// Ae_h [256 x 512]: k<256: c(k(y+127)) ; k>=256: -s((k-256)(y+127))
__global__ void prep_Ae(f16* __restrict__ Ae) {
    int idx = blockIdx.x * 256 + threadIdx.x;   // 256*512
    int y = idx >> 9, k = idx & 511;
    float c, s;
    if (k < 256) { twid(k, y + CROP, c, s);       Ae[idx] = (f16)c;    }
    else         { twid(k - 256, y + CROP, c, s); Ae[idx] = (f16)(-s); }
}
// imT [16][256x256]: imT[bc][x][y] = im[bc][y][x]  (f16)
__global__ void prep_imT(const float* __restrict__ im, f16* __restrict__ imT) {
    int idx = blockIdx.x * 256 + threadIdx.x;
    int bc = idx >> 16, r = idx & 65535;
    int y = r >> 8, x = r & 255;
    imT[(size_t)bc * 65536 + x * 256 + y] = (f16)im[idx];
}
// zero pad cols 1022,1023 of feats (stage-D GEMM reads them as K)
__global__ void zero_pad1024(f16* __restrict__ buf, int rows) {
    int r = blockIdx.x * 256 + threadIdx.x;
    if (r < rows) {
        buf[(size_t)r * 1024 + 1022] = (f16)0.f;
        buf[(size_t)r * 1024 + 1023] = (f16)0.f;
    }
}

// ---------------------------------------------------------------------------
// Stage C: Hermitian channel mix. h[u,v] = sum_c F[u,v] * Wh[u,v],
// Wh = (W[u,v] + conj(W[-u,-v]))/2 computed on the fly. u in [0,256).
// ---------------------------------------------------------------------------
__global__ void cmul_h(const f16* __restrict__ F, const float2* __restrict__ W,
                       f16* __restrict__ feats) {
    int idx = blockIdx.x * 256 + threadIdx.x;
    if (idx >= 256 * NN) return;
    int u = idx / NN, v = idx - u * NN;
    int u2 = (u == 0) ? 0 : NN - u;
    int v2 = (v == 0) ? 0 : NN - v;
    float fr[BB][CINC], fi[BB][CINC];
    #pragma unroll
    for (int b = 0; b < BB; ++b)
        #pragma unroll
        for (int c = 0; c < CINC; ++c) {
            size_t row = ((size_t)((b * CINC + c) * 256 + u)) * 1024;
            fr[b][c] = (float)F[row + v];
            fi[b][c] = (float)F[row + NN + v];
        }
    #pragma unroll
    for (int o = 0; o < COUTC; ++o) {
        float whr[CINC], whi[CINC];
        #pragma unroll
        for (int c = 0; c < CINC; ++c) {
            size_t base = (size_t)(o * CINC + c) * NN;
            float2 w1 = W[(base + u)  * NN + v];
            float2 w2 = W[(base + u2) * NN + v2];
            whr[c] = 0.5f * (w1.x + w2.x);
            whi[c] = 0.5f * (w1.y - w2.y);
        }
        #pragma unroll
        for (int b = 0; b < BB; ++b) {
            float hr = 0.f, hi = 0.f;
            #pragma unroll
            for (int c = 0; c < CINC; ++c) {
                hr += fr[b][c] * whr[c] - fi[b][c] * whi[c];
                hi += fr[b][c] * whi[c] + fi[b][c] * whr[c];
            }
            size_t orow = ((size_t)((b * COUTC + o) * 256 + u)) * 1024;
            feats[orow + v]      = (f16)hr;
            feats[orow + NN + v] = (f16)hi;
        }
    }
}

// ---------------------------------------------------------------------------
// MFMA GEMM: 128x64 block tile, 4 waves (2x2) x 64x32 wave tile, BK=32,
// global_load_lds(16B) staging, unpadded LDS. A [M,K], Bt [N,K] row-major.
// All stage extents are exact multiples of the tile -> no epilogue guards.
// ---------------------------------------------------------------------------
#define GLB_PTR(p) ((const __attribute__((address_space(1))) unsigned int*)(p))
#define LDS_PTR(p) ((__attribute__((address_space(3))) unsigned int*)(p))
__device__ __forceinline__ void gld16(const f16* g, f16* l) {
    __builtin_amdgcn_global_load_lds(GLB_PTR(g), LDS_PTR(l), 16, 0, 0);
}

template<int EPI>
__global__ __launch_bounds__(256)
void gemm128x64(const f16* __restrict__ A, const f16* __restrict__ Bt,
                f16* __restrict__ Ch, float* __restrict__ Cf,
                const float* __restrict__ bias,
                int Kt, int ldA, int ldB, size_t sA, size_t sB) {
    __shared__ __align__(16) f16 As[128 * 32];   // 8 KB
    __shared__ __align__(16) f16 Bs[64 * 32];    // 4 KB

    const int z  = blockIdx.z;
    const int m0 = blockIdx.x * 128;
    const int n0 = blockIdx.y * 64;
    A  += (size_t)z * sA;
    Bt += (size_t)z * sB;

    const int t  = threadIdx.x;
    const int r4 = t >> 2;            // 0..63
    const int c8 = (t & 3) << 3;      // 0,8,16,24 (f16)
    const f16* Ap = A  + (size_t)(m0 + r4) * ldA + c8;
    const f16* Bp = Bt + (size_t)(n0 + r4) * ldB + c8;
    f16* lA = As + t * 8;
    f16* lB = Bs + t * 8;

    const int lane = t & 63, w = t >> 6;
    const int wm = (w >> 1) * 64, wn = (w & 1) * 32;
    const int col = lane & 15, quad = lane >> 4;
    const f16* a_base = As + (wm + col) * 32 + quad * 8;
    const f16* b_base = Bs + (wn + col) * 32 + quad * 8;

    f32x4 acc[4][2] = {};

    for (int kb = 0; kb < Kt; ++kb) {
        __syncthreads();
        gld16(Ap,            lA);
        gld16(Ap + 64 * ldA, lA + 2048);
        gld16(Bp,            lB);
        Ap += 32; Bp += 32;
        __syncthreads();
        f16x8 af[4], bf[2];
        #pragma unroll
        for (int i = 0; i < 4; ++i) af[i] = *(const f16x8*)(a_base + i * 16 * 32);
        #pragma unroll
        for (int j = 0; j < 2; ++j) bf[j] = *(const f16x8*)(b_base + j * 16 * 32);
        #pragma unroll
        for (int i = 0; i < 4; ++i)
            #pragma unroll
            for (int j = 0; j < 2; ++j)
                acc[i][j] = __builtin_amdgcn_mfma_f32_16x16x32_f16(af[i], bf[j], acc[i][j], 0, 0, 0);
    }

    #pragma unroll
    for (int i = 0; i < 4; ++i)
    #pragma unroll
    for (int j = 0; j < 2; ++j) {
        const int mbase = m0 + wm + i * 16 + quad * 4;
        const int ncol  = n0 + wn + j * 16 + col;
        #pragma unroll
        for (int r = 0; r < 4; ++r) {
            const int mm = mbase + r;
            const float val = acc[i][j][r];
            if constexpr (EPI == 0) {          // stage A -> T1 [z*256+u][512]
                int u = mm & 255;
                int slot = (mm < 256) ? ncol : 256 + ncol;
                Ch[((size_t)(z * 256 + u)) * 512 + slot] = (f16)val;
            } else if constexpr (EPI == 1) {   // stage B -> F [4096 x 1024]
                Ch[(size_t)mm * 1024 + ncol] = (f16)val;
            } else if constexpr (EPI == 2) {   // stage D -> T2t [bo*256+x][512]
                int bo = mm >> 8, u = mm & 255;
                int x    = (ncol < 256) ? ncol : ncol - 256;
                int slot = (ncol < 256) ? u : 256 + u;
                float sc = (u == 0) ? INV_NN2 : 2.f * INV_NN2;   // Hermitian pair weight
                Ch[((size_t)((bo << 8) + x)) * 512 + slot] = (f16)(val * sc);
            } else {                            // stage E -> out fp32
                int bo = ncol >> 8, x = ncol & 255;
                Cf[((size_t)bo * 256 + mm) * 256 + x] = val + bias[bo & 7];
            }
        }
    }
}

// ---------------------------------------------------------------------------
// kernel_launch
// ---------------------------------------------------------------------------
extern "C" void kernel_launch(void* const* d_in, const int* in_sizes, int n_in,
                              void* d_out, int out_size, void* d_ws, size_t ws_size,
                              hipStream_t stream) {
    const float*  im   = (const float*)d_in[0];
    const float2* W    = (const float2*)d_in[1];
    const float*  bias = (const float*)d_in[2];
    float*        out  = (float*)d_out;

    char* ws = (char*)d_ws;
    f16* Aa    = (f16*)(ws);                    // 512*256    = 256 KB
    f16* Bb    = (f16*)(ws + 262144);           // 1024*512   = 1 MB
    f16* Bd    = (f16*)(ws + 1310720);          // 512*1024   = 1 MB
    f16* Ae    = (f16*)(ws + 2359296);          // 256*512    = 256 KB
    f16* imT   = (f16*)(ws + 2621440);          // 16*256*256 = 2 MB
    f16* T1    = (f16*)(ws + 4718592);          // 4096*512   = 4 MB
    f16* F     = (f16*)(ws + 8912896);          // 4096*1024  = 8 MB
    f16* feats = (f16*)(ws + 17301504);         // 8192*1024  = 16 MB
    f16* T2t   = (f16*)(ws + 34078720);         // 8192*512   = 8 MB (end 42.5 MB)

    // preps
    prep_Aa <<<512,  256, 0, stream>>>(Aa);
    prep_Bb <<<2048, 256, 0, stream>>>(Bb);
    prep_Bd <<<2048, 256, 0, stream>>>(Bd);
    prep_Ae <<<512,  256, 0, stream>>>(Ae);
    prep_imT<<<4096, 256, 0, stream>>>(im, imT);
    zero_pad1024<<<32, 256, 0, stream>>>(feats, 8192);

    // Stage A: per bc: [512 x 256] = Aa_h x imT[bc] -> T1 [bc*256+u][x|256+x]
    gemm128x64<0><<<dim3(4, 4, 16), 256, 0, stream>>>(Aa, imT, T1, nullptr, nullptr,
                                                      8, 256, 256, 0, 65536);
    // Stage B: [4096 x 1024] = T1 x Bb -> F [bc*256+u][v|511+v]
    gemm128x64<1><<<dim3(32, 16, 1), 256, 0, stream>>>(T1, Bb, F, nullptr, nullptr,
                                                       16, 512, 512, 0, 0);
    // Stage C: Hermitian channel mix -> feats [bo*256+u][v|511+v] (pad zeroed)
    cmul_h<<<(256 * NN + 255) / 256, 256, 0, stream>>>(F, W, feats);
    // Stage D: [8192 x 512] = feats x Bd -> T2t [bo*256+x][u|256+u], g_u/N^2 folded
    gemm128x64<2><<<dim3(64, 8, 1), 256, 0, stream>>>(feats, Bd, T2t, nullptr, nullptr,
                                                      32, 1024, 1024, 0, 0);
    // Stage E: [256 x 8192] = Ae_h x T2t + bias -> out
    gemm128x64<3><<<dim3(2, 128, 1), 256, 0, stream>>>(Ae, T2t, nullptr, out, bias,
                                                       16, 512, 512, 0, 0);
}

// Round 6
// 170.595 us; speedup vs baseline: 40.3581x; 1.0664x over previous
//
#include <hip/hip_runtime.h>
#include <math.h>

#define NN 511
#define HH 256
#define BB 4
#define CINC 4
#define COUTC 8
#define CROP 127
#define INV_NN2 (1.0f / ((float)NN * (float)NN))

typedef _Float16 f16;
typedef _Float16 f16x8 __attribute__((ext_vector_type(8)));
typedef float    f32x4 __attribute__((ext_vector_type(4)));

// 32-bit twiddle: all products < 2^31.  forward twiddle = c - i*s
__device__ __forceinline__ void twid(int a, int b, float& c, float& s) {
    int m = (a * b) % NN;
    float phi = (float)(2.0 * M_PI / (double)NN) * (float)m;
    __sincosf(phi, &s, &c);
}

// ---------------------------------------------------------------------------
// ONE fused prep kernel: builds Aa, Bb, Bd, Ae, imT, zeroes feats pad cols.
// Ranges (element offsets):
//   Aa  [512 x 256]            :       0 .. 131072
//   Bb  [1024 x 512] (N,K)     :  131072 .. 655360
//   Bd  [512 x 1024] (N,K)     :  655360 .. 1179648
//   Ae  [256 x 512]            : 1179648 .. 1310720
//   imT [16][256x256] transpose: 1310720 .. 2359296
//   feats pad (8192 rows x 2)  : 2359296 .. 2375680
// ---------------------------------------------------------------------------
__global__ void prep_all(const float* __restrict__ im,
                         f16* __restrict__ Aa, f16* __restrict__ Bb,
                         f16* __restrict__ Bd, f16* __restrict__ Ae,
                         f16* __restrict__ imT, f16* __restrict__ feats) {
    int idx = blockIdx.x * 256 + threadIdx.x;
    if (idx < 131072) {                       // Aa_h [512 x 256]
        int m = idx >> 8, y = idx & 255;
        float c, s;
        if (m < 256) { twid(m, y, c, s);       Aa[idx] = (f16)c;    }
        else         { twid(m - 256, y, c, s); Aa[idx] = (f16)(-s); }
    } else if (idx < 655360) {                // Bb_t [1024 x 512]
        int i = idx - 131072;
        int n = i >> 9, k = i & 511;
        float v = 0.f;
        if (n < 2 * NN) {
            int vv = (n < NN) ? n : n - NN;
            int x  = k & 255;
            float c, s; twid(vv, x, c, s);
            if (n < NN) v = (k < 256) ? c : s;
            else        v = (k < 256) ? -s : c;
        }
        Bb[i] = (f16)v;
    } else if (idx < 1179648) {               // Bd_t [512 x 1024]
        int i = idx - 655360;
        int n = i >> 10, k = i & 1023;
        float v = 0.f;
        if (k < 2 * NN) {
            int x  = n & 255;
            int vv = (k < NN) ? k : k - NN;
            float c, s; twid(vv, x + CROP, c, s);
            if (n < 256) v = (k < NN) ? c : -s;
            else         v = (k < NN) ? s : c;
        }
        Bd[i] = (f16)v;
    } else if (idx < 1310720) {               // Ae_h [256 x 512]
        int i = idx - 1179648;
        int y = i >> 9, k = i & 511;
        float c, s;
        if (k < 256) { twid(k, y + CROP, c, s);       Ae[i] = (f16)c;    }
        else         { twid(k - 256, y + CROP, c, s); Ae[i] = (f16)(-s); }
    } else if (idx < 2359296) {               // imT transpose
        int i = idx - 1310720;
        int bc = i >> 16, r = i & 65535;
        int y = r >> 8, x = r & 255;
        imT[(size_t)bc * 65536 + x * 256 + y] = (f16)im[i];
    } else if (idx < 2375680) {               // feats pad cols 1022/1023
        int i = idx - 2359296;
        feats[(size_t)(i >> 1) * 1024 + 1022 + (i & 1)] = (f16)0.f;
    }
}

// ---------------------------------------------------------------------------
// Stage C: Hermitian channel mix. h[u,v] = sum_c F[u,v]*Wh[u,v],
// Wh = (W[u,v]+conj(W[-u,-v]))/2 on the fly. u in [0,256).
// ---------------------------------------------------------------------------
__global__ void cmul_h(const f16* __restrict__ F, const float2* __restrict__ W,
                       f16* __restrict__ feats) {
    int idx = blockIdx.x * 256 + threadIdx.x;
    if (idx >= 256 * NN) return;
    int u = idx / NN, v = idx - u * NN;
    int u2 = (u == 0) ? 0 : NN - u;
    int v2 = (v == 0) ? 0 : NN - v;
    float fr[BB][CINC], fi[BB][CINC];
    #pragma unroll
    for (int b = 0; b < BB; ++b)
        #pragma unroll
        for (int c = 0; c < CINC; ++c) {
            size_t row = ((size_t)((b * CINC + c) * 256 + u)) * 1024;
            fr[b][c] = (float)F[row + v];
            fi[b][c] = (float)F[row + NN + v];
        }
    #pragma unroll
    for (int o = 0; o < COUTC; ++o) {
        float whr[CINC], whi[CINC];
        #pragma unroll
        for (int c = 0; c < CINC; ++c) {
            size_t base = (size_t)(o * CINC + c) * NN;
            float2 w1 = W[(base + u)  * NN + v];
            float2 w2 = W[(base + u2) * NN + v2];
            whr[c] = 0.5f * (w1.x + w2.x);
            whi[c] = 0.5f * (w1.y - w2.y);
        }
        #pragma unroll
        for (int b = 0; b < BB; ++b) {
            float hr = 0.f, hi = 0.f;
            #pragma unroll
            for (int c = 0; c < CINC; ++c) {
                hr += fr[b][c] * whr[c] - fi[b][c] * whi[c];
                hi += fr[b][c] * whi[c] + fi[b][c] * whr[c];
            }
            size_t orow = ((size_t)((b * COUTC + o) * 256 + u)) * 1024;
            feats[orow + v]      = (f16)hr;
            feats[orow + NN + v] = (f16)hi;
        }
    }
}

// ---------------------------------------------------------------------------
// MFMA GEMM: 128x64 block tile, 4 waves (2x2) x 64x32, BK=64.
// 16 MFMA + 6 global_load_lds(16B) per 2-barrier iteration.
// XOR-swizzled LDS: global k-chunk c of row r stored at slot c^(r&7) --
// applied on the FETCH side (global address), LDS dst stays lane-contiguous
// (required by global_load_lds wave-uniform-base semantics). MFMA ds_read
// then spreads over 8 bank groups -> 2-way conflicts only (free).
// A [M,K], Bt [N,K] row-major; ldA/ldB multiples of 8.
// ---------------------------------------------------------------------------
#define GLB_PTR(p) ((const __attribute__((address_space(1))) unsigned int*)(p))
#define LDS_PTR(p) ((__attribute__((address_space(3))) unsigned int*)(p))
__device__ __forceinline__ void gld16(const f16* g, f16* l) {
    __builtin_amdgcn_global_load_lds(GLB_PTR(g), LDS_PTR(l), 16, 0, 0);
}

template<int EPI>
__global__ __launch_bounds__(256)
void gemm128x64(const f16* __restrict__ A, const f16* __restrict__ Bt,
                f16* __restrict__ Ch, float* __restrict__ Cf,
                const float* __restrict__ bias,
                int Kt, int ldA, int ldB, size_t sA, size_t sB) {
    __shared__ __align__(16) f16 As[128 * 64];   // 16 KB
    __shared__ __align__(16) f16 Bs[64 * 64];    // 8 KB

    const int z  = blockIdx.z;
    const int m0 = blockIdx.x * 128;
    const int n0 = blockIdx.y * 64;
    A  += (size_t)z * sA;
    Bt += (size_t)z * sB;

    const int t    = threadIdx.x;
    const int row  = t >> 3;                  // 0..31 per staging round
    const int slot = t & 7;                   // 16B chunk slot
    const int kg   = (slot ^ (row & 7)) << 3; // swizzled global k-offset (f16)
    const f16* Ap = A  + (size_t)(m0 + row) * ldA + kg;
    const f16* Bp = Bt + (size_t)(n0 + row) * ldB + kg;
    f16* lA = As + t * 8;                     // lane-contiguous
    f16* lB = Bs + t * 8;

    const int lane = t & 63, w = t >> 6;
    const int wm = (w >> 1) * 64, wn = (w & 1) * 32;
    const int col = lane & 15, quad = lane >> 4;
    const int aswz = col & 7;
    // within-row f16 offsets of the two k-halves' chunks (chunk = kk*4+quad)
    const int offK0 = ((quad)     ^ aswz) << 3;
    const int offK1 = ((4 + quad) ^ aswz) << 3;
    const f16* a_col = As + (wm + col) * 64;
    const f16* b_col = Bs + (wn + col) * 64;

    f32x4 acc[4][2] = {};

    for (int kb = 0; kb < Kt; ++kb) {
        __syncthreads();
        gld16(Ap,             lA);
        gld16(Ap +  32 * ldA, lA + 2048);
        gld16(Ap +  64 * ldA, lA + 4096);
        gld16(Ap +  96 * ldA, lA + 6144);
        gld16(Bp,             lB);
        gld16(Bp +  32 * ldB, lB + 2048);
        Ap += 64; Bp += 64;
        __syncthreads();
        f16x8 af[4][2], bf[2][2];
        #pragma unroll
        for (int i = 0; i < 4; ++i) {
            af[i][0] = *(const f16x8*)(a_col + i * 16 * 64 + offK0);
            af[i][1] = *(const f16x8*)(a_col + i * 16 * 64 + offK1);
        }
        #pragma unroll
        for (int j = 0; j < 2; ++j) {
            bf[j][0] = *(const f16x8*)(b_col + j * 16 * 64 + offK0);
            bf[j][1] = *(const f16x8*)(b_col + j * 16 * 64 + offK1);
        }
        #pragma unroll
        for (int kk = 0; kk < 2; ++kk)
            #pragma unroll
            for (int i = 0; i < 4; ++i)
                #pragma unroll
                for (int j = 0; j < 2; ++j)
                    acc[i][j] = __builtin_amdgcn_mfma_f32_16x16x32_f16(
                        af[i][kk], bf[j][kk], acc[i][j], 0, 0, 0);
    }

    #pragma unroll
    for (int i = 0; i < 4; ++i)
    #pragma unroll
    for (int j = 0; j < 2; ++j) {
        const int mbase = m0 + wm + i * 16 + quad * 4;
        const int ncol  = n0 + wn + j * 16 + col;
        #pragma unroll
        for (int r = 0; r < 4; ++r) {
            const int mm = mbase + r;
            const float val = acc[i][j][r];
            if constexpr (EPI == 0) {          // stage A -> T1 [z*256+u][512]
                int u = mm & 255;
                int slotc = (mm < 256) ? ncol : 256 + ncol;
                Ch[((size_t)(z * 256 + u)) * 512 + slotc] = (f16)val;
            } else if constexpr (EPI == 1) {   // stage B -> F [4096 x 1024]
                Ch[(size_t)mm * 1024 + ncol] = (f16)val;
            } else if constexpr (EPI == 2) {   // stage D -> T2t [bo*256+x][512]
                int bo = mm >> 8, u = mm & 255;
                int x     = (ncol < 256) ? ncol : ncol - 256;
                int slotc = (ncol < 256) ? u : 256 + u;
                float sc = (u == 0) ? INV_NN2 : 2.f * INV_NN2;
                Ch[((size_t)((bo << 8) + x)) * 512 + slotc] = (f16)(val * sc);
            } else {                            // stage E -> out fp32
                int bo = ncol >> 8, x = ncol & 255;
                Cf[((size_t)bo * 256 + mm) * 256 + x] = val + bias[bo & 7];
            }
        }
    }
}

// ---------------------------------------------------------------------------
// kernel_launch
// ---------------------------------------------------------------------------
extern "C" void kernel_launch(void* const* d_in, const int* in_sizes, int n_in,
                              void* d_out, int out_size, void* d_ws, size_t ws_size,
                              hipStream_t stream) {
    const float*  im   = (const float*)d_in[0];
    const float2* W    = (const float2*)d_in[1];
    const float*  bias = (const float*)d_in[2];
    float*        out  = (float*)d_out;

    char* ws = (char*)d_ws;
    f16* Aa    = (f16*)(ws);                    // 512*256    = 256 KB
    f16* Bb    = (f16*)(ws + 262144);           // 1024*512   = 1 MB
    f16* Bd    = (f16*)(ws + 1310720);          // 512*1024   = 1 MB
    f16* Ae    = (f16*)(ws + 2359296);          // 256*512    = 256 KB
    f16* imT   = (f16*)(ws + 2621440);          // 16*256*256 = 2 MB
    f16* T1    = (f16*)(ws + 4718592);          // 4096*512   = 4 MB
    f16* F     = (f16*)(ws + 8912896);          // 4096*1024  = 8 MB
    f16* feats = (f16*)(ws + 17301504);         // 8192*1024  = 16 MB
    f16* T2t   = (f16*)(ws + 34078720);         // 8192*512   = 8 MB

    // fused preps (2,375,680 elements)
    prep_all<<<9280, 256, 0, stream>>>(im, Aa, Bb, Bd, Ae, imT, feats);

    // Stage A: per bc: [512 x 256] = Aa_h x imT[bc] -> T1
    gemm128x64<0><<<dim3(4, 4, 16), 256, 0, stream>>>(Aa, imT, T1, nullptr, nullptr,
                                                      4, 256, 256, 0, 65536);
    // Stage B: [4096 x 1024] = T1 x Bb -> F
    gemm128x64<1><<<dim3(32, 16, 1), 256, 0, stream>>>(T1, Bb, F, nullptr, nullptr,
                                                       8, 512, 512, 0, 0);
    // Stage C: Hermitian channel mix -> feats
    cmul_h<<<(256 * NN + 255) / 256, 256, 0, stream>>>(F, W, feats);
    // Stage D: [8192 x 512] = feats x Bd -> T2t (g_u/N^2 folded)
    gemm128x64<2><<<dim3(64, 8, 1), 256, 0, stream>>>(feats, Bd, T2t, nullptr, nullptr,
                                                      16, 1024, 1024, 0, 0);
    // Stage E: [256 x 8192] = Ae_h x T2t + bias -> out
    gemm128x64<3><<<dim3(2, 128, 1), 256, 0, stream>>>(Ae, T2t, nullptr, out, bias,
                                                       8, 512, 512, 0, 0);
}

// Round 7
// 157.314 us; speedup vs baseline: 43.7653x; 1.0844x over previous
//
#include <hip/hip_runtime.h>
#include <math.h>

#define NN 511
#define HH 256
#define BB 4
#define CINC 4
#define COUTC 8
#define CROP 127
#define INV_NN2 (1.0f / ((float)NN * (float)NN))

typedef _Float16 f16;
typedef _Float16 f16x2 __attribute__((ext_vector_type(2)));
typedef _Float16 f16x8 __attribute__((ext_vector_type(8)));
typedef float    f32x4 __attribute__((ext_vector_type(4)));

// 32-bit twiddle: all products < 2^31.  forward twiddle = c - i*s
__device__ __forceinline__ void twid(int a, int b, float& c, float& s) {
    int m = (a * b) % NN;
    float phi = (float)(2.0 * M_PI / (double)NN) * (float)m;
    __sincosf(phi, &s, &c);
}

// ---------------------------------------------------------------------------
// ONE fused prep kernel.  Element ranges:
//   Aa  [512 x 256]              :       0 .. 131072
//   Bb_t [1024 x 512] (n=2v+ri)  :  131072 .. 655360
//   Bd_t [512 x 1024] (k=2v+ri)  :  655360 .. 1179648
//   Ae  [256 x 512]              : 1179648 .. 1310720
//   imT [16][256x256] transpose  : 1310720 .. 2359296
// ---------------------------------------------------------------------------
__global__ void prep_all(const float* __restrict__ im,
                         f16* __restrict__ Aa, f16* __restrict__ Bb,
                         f16* __restrict__ Bd, f16* __restrict__ Ae,
                         f16* __restrict__ imT) {
    int idx = blockIdx.x * 256 + threadIdx.x;
    if (idx < 131072) {                       // Aa_h [512 x 256]
        int m = idx >> 8, y = idx & 255;
        float c, s;
        if (m < 256) { twid(m, y, c, s);       Aa[idx] = (f16)c;    }
        else         { twid(m - 256, y, c, s); Aa[idx] = (f16)(-s); }
    } else if (idx < 655360) {                // Bb_t [1024 x 512], n = 2v+ri
        int i = idx - 131072;
        int n = i >> 9, k = i & 511;
        int v = n >> 1, ri = n & 1;
        float val = 0.f;
        if (v < NN) {
            int x = k & 255;
            float c, s; twid(v, x, c, s);
            if (ri == 0) val = (k < 256) ? c  : s;   // Fr = sum T1r*c + T1i*s
            else         val = (k < 256) ? -s : c;   // Fi = sum -T1r*s + T1i*c
        }
        Bb[i] = (f16)val;
    } else if (idx < 1179648) {               // Bd_t [512 x 1024], k = 2v+ri
        int i = idx - 655360;
        int n = i >> 10, k = i & 1023;
        int v = k >> 1, ri = k & 1;
        float val = 0.f;
        if (v < NN) {
            int x = n & 255;
            float c, s; twid(v, x + CROP, c, s);
            if (ri == 0) val = (n < 256) ? c  : s;   // h_r coeff (T2r | T2i)
            else         val = (n < 256) ? -s : c;   // h_i coeff
        }
        Bd[i] = (f16)val;
    } else if (idx < 1310720) {               // Ae_h [256 x 512]
        int i = idx - 1179648;
        int y = i >> 9, k = i & 511;
        float c, s;
        if (k < 256) { twid(k, y + CROP, c, s);       Ae[i] = (f16)c;    }
        else         { twid(k - 256, y + CROP, c, s); Ae[i] = (f16)(-s); }
    } else if (idx < 2359296) {               // imT transpose
        int i = idx - 1310720;
        int bc = i >> 16, r = i & 65535;
        int y = r >> 8, x = r & 255;
        imT[(size_t)bc * 65536 + x * 256 + y] = (f16)im[i];
    }
}

// ---------------------------------------------------------------------------
// Shared GEMM machinery: 128x64 block tile, 4 waves (2x2) x 64x32, BK=64,
// global_load_lds(16B) staging, XOR-swizzled k-chunks (fetch-side permute,
// LDS stays lane-contiguous). A [M,K], Bt [N,K] row-major.
// ---------------------------------------------------------------------------
#define GLB_PTR(p) ((const __attribute__((address_space(1))) unsigned int*)(p))
#define LDS_PTR(p) ((__attribute__((address_space(3))) unsigned int*)(p))
__device__ __forceinline__ void gld16(const f16* g, f16* l) {
    __builtin_amdgcn_global_load_lds(GLB_PTR(g), LDS_PTR(l), 16, 0, 0);
}

// ---------------------------------------------------------------------------
// Generic GEMM for stages A, D, E (epilogue per stage).
// ---------------------------------------------------------------------------
template<int EPI>
__global__ __launch_bounds__(256)
void gemm128x64(const f16* __restrict__ A, const f16* __restrict__ Bt,
                f16* __restrict__ Ch, float* __restrict__ Cf,
                const float* __restrict__ bias,
                int Kt, int ldA, int ldB, size_t sA, size_t sB) {
    __shared__ __align__(16) f16 As[128 * 64];   // 16 KB
    __shared__ __align__(16) f16 Bs[64 * 64];    // 8 KB

    const int z  = blockIdx.z;
    const int m0 = blockIdx.x * 128;
    const int n0 = blockIdx.y * 64;
    A  += (size_t)z * sA;
    Bt += (size_t)z * sB;

    const int t    = threadIdx.x;
    const int row  = t >> 3;
    const int slot = t & 7;
    const int kg   = (slot ^ (row & 7)) << 3;
    const f16* Ap = A  + (size_t)(m0 + row) * ldA + kg;
    const f16* Bp = Bt + (size_t)(n0 + row) * ldB + kg;
    f16* lA = As + t * 8;
    f16* lB = Bs + t * 8;

    const int lane = t & 63, w = t >> 6;
    const int wm = (w >> 1) * 64, wn = (w & 1) * 32;
    const int col = lane & 15, quad = lane >> 4;
    const int aswz = col & 7;
    const int offK0 = ((quad)     ^ aswz) << 3;
    const int offK1 = ((4 + quad) ^ aswz) << 3;
    const f16* a_col = As + (wm + col) * 64;
    const f16* b_col = Bs + (wn + col) * 64;

    f32x4 acc[4][2] = {};

    for (int kb = 0; kb < Kt; ++kb) {
        __syncthreads();
        gld16(Ap,             lA);
        gld16(Ap +  32 * ldA, lA + 2048);
        gld16(Ap +  64 * ldA, lA + 4096);
        gld16(Ap +  96 * ldA, lA + 6144);
        gld16(Bp,             lB);
        gld16(Bp +  32 * ldB, lB + 2048);
        Ap += 64; Bp += 64;
        __syncthreads();
        f16x8 af[4][2], bf[2][2];
        #pragma unroll
        for (int i = 0; i < 4; ++i) {
            af[i][0] = *(const f16x8*)(a_col + i * 16 * 64 + offK0);
            af[i][1] = *(const f16x8*)(a_col + i * 16 * 64 + offK1);
        }
        #pragma unroll
        for (int j = 0; j < 2; ++j) {
            bf[j][0] = *(const f16x8*)(b_col + j * 16 * 64 + offK0);
            bf[j][1] = *(const f16x8*)(b_col + j * 16 * 64 + offK1);
        }
        #pragma unroll
        for (int kk = 0; kk < 2; ++kk)
            #pragma unroll
            for (int i = 0; i < 4; ++i)
                #pragma unroll
                for (int j = 0; j < 2; ++j)
                    acc[i][j] = __builtin_amdgcn_mfma_f32_16x16x32_f16(
                        af[i][kk], bf[j][kk], acc[i][j], 0, 0, 0);
    }

    #pragma unroll
    for (int i = 0; i < 4; ++i)
    #pragma unroll
    for (int j = 0; j < 2; ++j) {
        const int mbase = m0 + wm + i * 16 + quad * 4;
        const int ncol  = n0 + wn + j * 16 + col;
        #pragma unroll
        for (int r = 0; r < 4; ++r) {
            const int mm = mbase + r;
            const float val = acc[i][j][r];
            if constexpr (EPI == 0) {          // stage A -> T1 rows u*16+bc
                int u = mm & 255;
                int slotc = (mm < 256) ? ncol : 256 + ncol;
                Ch[((size_t)(u * 16 + z)) * 512 + slotc] = (f16)val;
            } else if constexpr (EPI == 2) {   // stage D -> T2t [bo*256+x][512]
                int bo = mm >> 8, u = mm & 255;
                int x     = (ncol < 256) ? ncol : ncol - 256;
                int slotc = (ncol < 256) ? u : 256 + u;
                float sc = (u == 0) ? INV_NN2 : 2.f * INV_NN2;
                Ch[((size_t)((bo << 8) + x)) * 512 + slotc] = (f16)(val * sc);
            } else {                            // stage E -> out fp32
                int bo = ncol >> 8, x = ncol & 255;
                Cf[((size_t)bo * 256 + mm) * 256 + x] = val + bias[bo & 7];
            }
        }
    }
}

// ---------------------------------------------------------------------------
// Stage B + channel mix fused.
// GEMM: [4096 m=(u*16+bc)] x [1024 n=(2v+ri)] over K=512 -> F tile in regs.
// Epilogue: acc -> LDS (F tile, all 16 bc block-local), then 256 threads
// each own one (u,v): Hermitian mix with W, write all 32 (b,o) feats values.
// ---------------------------------------------------------------------------
#define LSTR 68   // LDS row stride (f16): breaks quad-stride bank pattern
__global__ __launch_bounds__(256)
void gemmB_fused(const f16* __restrict__ A, const f16* __restrict__ Bt,
                 const float2* __restrict__ W, f16* __restrict__ feats) {
    __shared__ __align__(16) char smem[24576];
    f16* As = (f16*)smem;                 // 16 KB
    f16* Bs = (f16*)(smem + 16384);       // 8 KB
    f16* Ls = (f16*)smem;                 // epilogue overlay: 128*68*2 = 17.4 KB

    const int m0 = blockIdx.x * 128;      // u0 = blockIdx.x*8
    const int n0 = blockIdx.y * 64;       // v0 = blockIdx.y*32

    const int t    = threadIdx.x;
    const int row  = t >> 3;
    const int slot = t & 7;
    const int kg   = (slot ^ (row & 7)) << 3;
    const f16* Ap = A  + (size_t)(m0 + row) * 512 + kg;
    const f16* Bp = Bt + (size_t)(n0 + row) * 512 + kg;
    f16* lA = As + t * 8;
    f16* lB = Bs + t * 8;

    const int lane = t & 63, w = t >> 6;
    const int wm = (w >> 1) * 64, wn = (w & 1) * 32;
    const int col = lane & 15, quad = lane >> 4;
    const int aswz = col & 7;
    const int offK0 = ((quad)     ^ aswz) << 3;
    const int offK1 = ((4 + quad) ^ aswz) << 3;
    const f16* a_col = As + (wm + col) * 64;
    const f16* b_col = Bs + (wn + col) * 64;

    f32x4 acc[4][2] = {};

    for (int kb = 0; kb < 8; ++kb) {
        __syncthreads();
        gld16(Ap,            lA);
        gld16(Ap + 32 * 512, lA + 2048);
        gld16(Ap + 64 * 512, lA + 4096);
        gld16(Ap + 96 * 512, lA + 6144);
        gld16(Bp,            lB);
        gld16(Bp + 32 * 512, lB + 2048);
        Ap += 64; Bp += 64;
        __syncthreads();
        f16x8 af[4][2], bf[2][2];
        #pragma unroll
        for (int i = 0; i < 4; ++i) {
            af[i][0] = *(const f16x8*)(a_col + i * 16 * 64 + offK0);
            af[i][1] = *(const f16x8*)(a_col + i * 16 * 64 + offK1);
        }
        #pragma unroll
        for (int j = 0; j < 2; ++j) {
            bf[j][0] = *(const f16x8*)(b_col + j * 16 * 64 + offK0);
            bf[j][1] = *(const f16x8*)(b_col + j * 16 * 64 + offK1);
        }
        #pragma unroll
        for (int kk = 0; kk < 2; ++kk)
            #pragma unroll
            for (int i = 0; i < 4; ++i)
                #pragma unroll
                for (int j = 0; j < 2; ++j)
                    acc[i][j] = __builtin_amdgcn_mfma_f32_16x16x32_f16(
                        af[i][kk], bf[j][kk], acc[i][j], 0, 0, 0);
    }

    // acc -> LDS (F tile, f16)
    __syncthreads();                      // waves done reading As/Bs
    #pragma unroll
    for (int i = 0; i < 4; ++i)
    #pragma unroll
    for (int j = 0; j < 2; ++j) {
        const int ml = wm + i * 16 + quad * 4;
        const int nl = wn + j * 16 + col;
        #pragma unroll
        for (int r = 0; r < 4; ++r)
            Ls[(ml + r) * LSTR + nl] = (f16)acc[i][j][r];
    }
    __syncthreads();

    // Hermitian channel mix: one thread per (u,v) in tile
    const int du = t >> 5, dv = t & 31;
    const int u = (m0 >> 4) + du;         // m0/16 = u0
    const int v = (n0 >> 1) + dv;         // n0/2  = v0
    const int u2 = (u == 0) ? 0 : NN - u;
    const int v2 = (v == 0) ? 0 : NN - v;

    float fr[16], fi[16];
    #pragma unroll
    for (int bc = 0; bc < 16; ++bc) {
        f16x2 p = *(const f16x2*)&Ls[(du * 16 + bc) * LSTR + dv * 2];
        fr[bc] = (float)p.x;
        fi[bc] = (float)p.y;
    }

    #pragma unroll
    for (int o = 0; o < COUTC; ++o) {
        float whr[CINC], whi[CINC];
        #pragma unroll
        for (int c = 0; c < CINC; ++c) {
            size_t base = (size_t)(o * CINC + c) * NN;
            float2 w1 = W[(base + u)  * NN + v];
            float2 w2 = W[(base + u2) * NN + v2];
            whr[c] = 0.5f * (w1.x + w2.x);
            whi[c] = 0.5f * (w1.y - w2.y);
        }
        #pragma unroll
        for (int b = 0; b < BB; ++b) {
            float hr = 0.f, hi = 0.f;
            #pragma unroll
            for (int c = 0; c < CINC; ++c) {
                hr += fr[b * 4 + c] * whr[c] - fi[b * 4 + c] * whi[c];
                hi += fr[b * 4 + c] * whi[c] + fi[b * 4 + c] * whr[c];
            }
            f16x2 outp; outp.x = (f16)hr; outp.y = (f16)hi;
            *(f16x2*)&feats[((size_t)((b * COUTC + o) * 256 + u)) * 1024 + v * 2] = outp;
        }
    }
}

// ---------------------------------------------------------------------------
// kernel_launch
// ---------------------------------------------------------------------------
extern "C" void kernel_launch(void* const* d_in, const int* in_sizes, int n_in,
                              void* d_out, int out_size, void* d_ws, size_t ws_size,
                              hipStream_t stream) {
    const float*  im   = (const float*)d_in[0];
    const float2* W    = (const float2*)d_in[1];
    const float*  bias = (const float*)d_in[2];
    float*        out  = (float*)d_out;

    char* ws = (char*)d_ws;
    f16* Aa    = (f16*)(ws);                    // 512*256    = 256 KB
    f16* Bb    = (f16*)(ws + 262144);           // 1024*512   = 1 MB
    f16* Bd    = (f16*)(ws + 1310720);          // 512*1024   = 1 MB
    f16* Ae    = (f16*)(ws + 2359296);          // 256*512    = 256 KB
    f16* imT   = (f16*)(ws + 2621440);          // 16*256*256 = 2 MB
    f16* T1    = (f16*)(ws + 4718592);          // 4096*512   = 4 MB
    f16* feats = (f16*)(ws + 8912896);          // 8192*1024  = 16 MB
    f16* T2t   = (f16*)(ws + 25690112);         // 8192*512   = 8 MB (end 33.7 MB)

    // fused preps (2,359,296 elements)
    prep_all<<<9216, 256, 0, stream>>>(im, Aa, Bb, Bd, Ae, imT);

    // Stage A: per bc: [512 x 256] = Aa_h x imT[bc] -> T1 rows u*16+bc
    gemm128x64<0><<<dim3(4, 4, 16), 256, 0, stream>>>(Aa, imT, T1, nullptr, nullptr,
                                                      4, 256, 256, 0, 65536);
    // Stage B + mix: [4096 x 1024] GEMM -> in-LDS F -> Hermitian mix -> feats
    gemmB_fused<<<dim3(32, 16), 256, 0, stream>>>(T1, Bb, W, feats);

    // Stage D: [8192 x 512] = feats x Bd -> T2t (g_u/N^2 folded)
    gemm128x64<2><<<dim3(64, 8, 1), 256, 0, stream>>>(feats, Bd, T2t, nullptr, nullptr,
                                                      16, 1024, 1024, 0, 0);
    // Stage E: [256 x 8192] = Ae_h x T2t + bias -> out
    gemm128x64<3><<<dim3(2, 128, 1), 256, 0, stream>>>(Ae, T2t, nullptr, out, bias,
                                                       8, 512, 512, 0, 0);
}